// Round 7
// baseline (567.036 us; speedup 1.0000x reference)
//
#include <hip/hip_runtime.h>
#include <math.h>

// Problem dims (fixed by the reference)
#define S_DIM 4096
#define H_DIM 4096
#define HC_N 4
#define HD_DIM 16384   // HC_N * H_DIM
#define MIXN 24        // (2+HC)*HC
#define SINK_IT 20

typedef float f32x4 __attribute__((ext_vector_type(4)));
typedef __bf16 bf16x8 __attribute__((ext_vector_type(8)));
typedef unsigned short u16x8 __attribute__((ext_vector_type(8)));
typedef unsigned short u16x4 __attribute__((ext_vector_type(4)));

__device__ __forceinline__ unsigned short f2bf(float f) {
  unsigned u = __builtin_bit_cast(unsigned, f);
  u += 0x7FFFu + ((u >> 16) & 1u);   // round-to-nearest-even
  return (unsigned short)(u >> 16);
}
__device__ __forceinline__ float bf2f(unsigned short h) {
  return __builtin_bit_cast(float, (unsigned)h << 16);
}

// ---------------------------------------------------------------------------
// K0: w_inner fp32 -> bf16
__global__ __launch_bounds__(256) void k_w2bf(const float* __restrict__ w,
                                              unsigned short* __restrict__ wb) {
  const size_t i = (size_t)(blockIdx.x * 256 + threadIdx.x) * 8;
  f32x4 a = *(const f32x4*)(w + i);
  f32x4 b = *(const f32x4*)(w + i + 4);
  u16x8 o;
  o[0] = f2bf(a.x); o[1] = f2bf(a.y); o[2] = f2bf(a.z); o[3] = f2bf(a.w);
  o[4] = f2bf(b.x); o[5] = f2bf(b.y); o[6] = f2bf(b.z); o[7] = f2bf(b.w);
  *(u16x8*)(wb + i) = o;
}

// ---------------------------------------------------------------------------
// K1: per-row mixes + sumsq + (fused) sigmoid/Sinkhorn gates.
// 8 rows per block (halves fn L2 traffic vs 4 rows), m-split across waves
// (wave w owns m in [6w,6w+6), acc[8][6]=48 VGPR). Register-prefetch double
// staging: next 512-float/row chunk's global loads issue between the two
// barriers, hiding HBM latency under the FMA + fn-read phase (the old
// version's syncthreads lockstep made hs(41us)+fn(46us)+VALU(20us) additive).
// All fp32 math (matches proven absmax 0.03125).
__global__ __launch_bounds__(256) void k_mixes(const float* __restrict__ hs,
                                               const float* __restrict__ fn,
                                               const float* __restrict__ hbase,
                                               const float* __restrict__ hscale,
                                               float* __restrict__ gates) {
  __shared__ __align__(16) float lds[8 * 512];    // 16KB: 8 rows x 512 floats
  __shared__ float smix[8][MIXN];
  __shared__ float sss[4][4];
  const int tid = threadIdx.x, lane = tid & 63, wave = tid >> 6;
  const int mb = wave * 6;
  const size_t base = (size_t)blockIdx.x * 8 * HD_DIM;

  // staging map: flat idx q*1024+tid*4 -> row=idx>>9, col=idx&511
  int srow[4], scol[4];
#pragma unroll
  for (int q = 0; q < 4; q++) {
    const int fidx = q * 1024 + tid * 4;
    srow[q] = fidx >> 9; scol[q] = fidx & 511;
  }

  float acc[8][6];
#pragma unroll
  for (int r = 0; r < 8; r++)
#pragma unroll
    for (int j = 0; j < 6; j++) acc[r][j] = 0.f;
  float ss[4] = {0.f, 0.f, 0.f, 0.f};

  f32x4 pf[4];
#pragma unroll
  for (int q = 0; q < 4; q++)
    pf[q] = *(const f32x4*)(hs + base + (size_t)srow[q] * HD_DIM + scol[q]);

  for (int it = 0; it < 32; ++it) {
    __syncthreads();   // previous compute done: LDS buffer free
#pragma unroll
    for (int q = 0; q < 4; q++) {
      const f32x4 v = pf[q];
      *(f32x4*)(&lds[q * 1024 + tid * 4]) = v;
      ss[q] += v.x * v.x + v.y * v.y + v.z * v.z + v.w * v.w;
    }
    if (it + 1 < 32) {
#pragma unroll
      for (int q = 0; q < 4; q++)
        pf[q] = *(const f32x4*)(hs + base + (size_t)srow[q] * HD_DIM + (it + 1) * 512 + scol[q]);
    }
    __syncthreads();   // buffer ready
#pragma unroll
    for (int ii = 0; ii < 2; ++ii) {
      const int c4 = (ii * 64 + lane) * 4;    // float offset within 512-row
      f32x4 h4[8];
#pragma unroll
      for (int r = 0; r < 8; r++) h4[r] = *(const f32x4*)(&lds[r * 512 + c4]);
#pragma unroll
      for (int j = 0; j < 6; j++) {
        const f32x4 fv = *(const f32x4*)(fn + (size_t)(mb + j) * HD_DIM + it * 512 + c4);
#pragma unroll
        for (int r = 0; r < 8; r++)
          acc[r][j] += h4[r].x * fv.x + h4[r].y * fv.y + h4[r].z * fv.z + h4[r].w * fv.w;
      }
    }
  }

  // reduce mix dots: wave owns its 6 m outright
#pragma unroll
  for (int r = 0; r < 8; r++)
#pragma unroll
    for (int j = 0; j < 6; j++) {
      float v = acc[r][j];
#pragma unroll
      for (int off = 32; off >= 1; off >>= 1) v += __shfl_xor(v, off, 64);
      if (lane == 0) smix[r][mb + j] = v;
    }
  // reduce sumsq: thread touched rows 2q + (tid>=128); waves 0,1 = even rows
#pragma unroll
  for (int q = 0; q < 4; q++) {
    float v = ss[q];
#pragma unroll
    for (int off = 32; off >= 1; off >>= 1) v += __shfl_xor(v, off, 64);
    if (lane == 0) sss[wave][q] = v;
  }
  __syncthreads();

  // fused gates: sigmoid + 20-iter Sinkhorn, one thread per row
  if (tid < 8) {
    const int r = tid, q = r >> 1;
    const float sumsq = (r & 1) ? (sss[2][q] + sss[3][q]) : (sss[0][q] + sss[1][q]);
    const float rs = rsqrtf(sumsq * (1.0f / HD_DIM) + 1e-6f);
    const float ps = hscale[0], qs = hscale[1], cs = hscale[2];
    float g[MIXN];
#pragma unroll
    for (int m = 0; m < MIXN; m++) {
      const float sc = (m < 4) ? ps : ((m < 8) ? qs : cs);
      const float x = smix[r][m] * rs * sc + hbase[m];
      g[m] = 1.0f / (1.0f + expf(-x)) + 1e-6f;
    }
    for (int t = 0; t < SINK_IT; t++) {
#pragma unroll
      for (int i = 0; i < 4; i++) {
        const float s = g[8 + i * 4 + 0] + g[8 + i * 4 + 1] + g[8 + i * 4 + 2] + g[8 + i * 4 + 3] + 1e-6f;
#pragma unroll
        for (int j = 0; j < 4; j++) g[8 + i * 4 + j] /= s;
      }
#pragma unroll
      for (int j = 0; j < 4; j++) {
        const float s = g[8 + 0 + j] + g[8 + 4 + j] + g[8 + 8 + j] + g[8 + 12 + j] + 1e-6f;
#pragma unroll
        for (int i = 0; i < 4; i++) g[8 + i * 4 + j] /= s;
      }
    }
    float* go = gates + (size_t)(blockIdx.x * 8 + r) * MIXN;
#pragma unroll
    for (int m = 0; m < MIXN; m++) go[m] = g[m];
  }
}

// ---------------------------------------------------------------------------
// K3: reduced = pre . hs  -> RMSNorm -> normed (bf16).  One block per row s.
__global__ __launch_bounds__(256) void k_reduce_norm(const float* __restrict__ hs,
                                                     const float* __restrict__ gates,
                                                     const float* __restrict__ nw,
                                                     unsigned short* __restrict__ normed) {
  const int s = blockIdx.x, tid = threadIdx.x;
  const int lane = tid & 63, wave = tid >> 6;
  const float* g = gates + (size_t)s * MIXN;
  const float p0 = g[0], p1 = g[1], p2 = g[2], p3 = g[3];
  const size_t base = (size_t)s * HC_N * H_DIM;

  f32x4 red[4];
  float ssq = 0.f;
#pragma unroll
  for (int it = 0; it < 4; ++it) {
    const int d4 = it * 256 + tid;
    f32x4 a = *(const f32x4*)(hs + base + (size_t)0 * H_DIM + (size_t)d4 * 4);
    f32x4 b = *(const f32x4*)(hs + base + (size_t)1 * H_DIM + (size_t)d4 * 4);
    f32x4 c = *(const f32x4*)(hs + base + (size_t)2 * H_DIM + (size_t)d4 * 4);
    f32x4 d = *(const f32x4*)(hs + base + (size_t)3 * H_DIM + (size_t)d4 * 4);
    f32x4 v = p0 * a + p1 * b + p2 * c + p3 * d;
    red[it] = v;
    ssq += v.x * v.x + v.y * v.y + v.z * v.z + v.w * v.w;
  }
#pragma unroll
  for (int off = 32; off >= 1; off >>= 1) ssq += __shfl_xor(ssq, off, 64);
  __shared__ float ls[4];
  if (lane == 0) ls[wave] = ssq;
  __syncthreads();
  const float tot = ls[0] + ls[1] + ls[2] + ls[3];
  const float nr = rsqrtf(tot * (1.0f / H_DIM) + 1e-6f);
#pragma unroll
  for (int it = 0; it < 4; ++it) {
    const int d4 = it * 256 + tid;
    f32x4 w = *(const f32x4*)(nw + (size_t)d4 * 4);
    f32x4 v = red[it] * nr;
    v = v * w;
    u16x4 o;
    o[0] = f2bf(v.x); o[1] = f2bf(v.y); o[2] = f2bf(v.z); o[3] = f2bf(v.w);
    *(u16x4*)(normed + (size_t)s * H_DIM + (size_t)d4 * 4) = o;
  }
}

// ---------------------------------------------------------------------------
// K4: bf16 GEMM  C[s][e] = sum_d A[s][d] * B[e][d]
// 256x256 tile, 8-phase schedule (frozen: three structurally different
// schedules measured identical ~197us; see round-5 theory).
__device__ __forceinline__ void gload_lds16(const unsigned short* g, unsigned short* l) {
  __builtin_amdgcn_global_load_lds(
      (const __attribute__((address_space(1))) unsigned int*)(const void*)g,
      (__attribute__((address_space(3))) unsigned int*)(void*)l, 16, 0, 0);
}

#define VMW(n) asm volatile("s_waitcnt vmcnt(" #n ")" ::: "memory")
#define BAR    asm volatile("s_barrier" ::: "memory")
#define LGK0   asm volatile("s_waitcnt lgkmcnt(0)" ::: "memory")
#define SCB    __builtin_amdgcn_sched_barrier(0)

__global__ __launch_bounds__(512, 2) void k_gemm(const unsigned short* __restrict__ A,
                                                 const unsigned short* __restrict__ B,
                                                 unsigned short* __restrict__ C) {
  __shared__ __align__(16) unsigned short sAbuf[2][2][256 * 32];
  __shared__ __align__(16) unsigned short sBbuf[2][2][256 * 32];
  const int tid = threadIdx.x;
  const int lane = tid & 63, wave = tid >> 6;

  // Bijective XCD swizzle (256 blocks % 8 == 0): XCD v owns bn in {2v,2v+1}.
  const int bid = blockIdx.x;
  const int v = bid & 7, u = bid >> 3;          // u in 0..31
  const int bm = u & 15, bn = v * 2 + (u >> 4);
  const int wm = wave >> 2, wn = wave & 3;      // 2x4 wave grid, 128x64 per wave

  // staging: wave stages rows [wave*32, +32) of a [256][32] k-half, 2 instr.
  // Pre-swizzled global source: chunk = (lane&3) ^ (row&3), row = lane>>2.
  const int srow = lane >> 2;                              // 0..15
  const int sk8 = (((lane & 3) ^ ((lane >> 2) & 3)) * 8);  // swizzled k-offset
  const unsigned short* gA = A + (size_t)(bm * 256 + wave * 32 + srow) * 4096 + sk8;
  const unsigned short* gB = B + (size_t)(bn * 256 + wave * 32 + srow) * 4096 + sk8;
  const int ld0 = wave * 1024 + lane * 8;   // element offset, instr 0 (linear dest)
  const int ld1 = ld0 + 512;                // rows +16..31

  f32x4 acc[8][4];
  f32x4 zero = {0.f, 0.f, 0.f, 0.f};
#pragma unroll
  for (int mf = 0; mf < 8; mf++)
#pragma unroll
    for (int nf = 0; nf < 4; nf++) acc[mf][nf] = zero;
  bf16x8 af[8];

  // fragment read: logical chunk = lane>>4, row&3 = lane&3 (row bases %4==0)
  const int frow = lane & 15;
  const int fk = (((lane >> 4) ^ (lane & 3)) * 8);   // swizzled read offset

#define PHASE_BODY(db, kh, nh, dostg, sdst, gsrc, t, skh) do {                  \
    if ((nh) == 0) {                                                            \
      _Pragma("unroll") for (int mf = 0; mf < 8; mf++)                          \
        af[mf] = *(const bf16x8*)&sAbuf[db][kh][(wm * 128 + mf * 16 + frow) * 32 + fk]; \
    }                                                                           \
    bf16x8 b0 = *(const bf16x8*)&sBbuf[db][kh][(wn * 64 + ((nh) * 2 + 0) * 16 + frow) * 32 + fk]; \
    bf16x8 b1 = *(const bf16x8*)&sBbuf[db][kh][(wn * 64 + ((nh) * 2 + 1) * 16 + frow) * 32 + fk]; \
    if (dostg) {                                                                \
      const unsigned short* _g = (gsrc) + (size_t)(t) * 64 + (skh) * 32;        \
      gload_lds16(_g,              (sdst) + ld0);                               \
      gload_lds16(_g + 16 * 4096,  (sdst) + ld1);                               \
    }                                                                           \
    SCB;                                                                        \
    BAR;                                                                        \
    LGK0;                                                                       \
    SCB;                                                                        \
    __builtin_amdgcn_s_setprio(1);                                              \
    _Pragma("unroll") for (int mf = 0; mf < 8; mf++) {                          \
      acc[mf][(nh) * 2 + 0] = __builtin_amdgcn_mfma_f32_16x16x32_bf16(af[mf], b0, acc[mf][(nh) * 2 + 0], 0, 0, 0); \
      acc[mf][(nh) * 2 + 1] = __builtin_amdgcn_mfma_f32_16x16x32_bf16(af[mf], b1, acc[mf][(nh) * 2 + 1], 0, 0, 0); \
    }                                                                           \
    __builtin_amdgcn_s_setprio(0);                                              \
    SCB;                                                                        \
  } while (0)

  // prologue: tile 0 -> db0 in order A-kh0, B-kh0, A-kh1, B-kh1
  gload_lds16(gA,                  &sAbuf[0][0][0] + ld0);
  gload_lds16(gA + 16 * 4096,      &sAbuf[0][0][0] + ld1);
  gload_lds16(gB,                  &sBbuf[0][0][0] + ld0);
  gload_lds16(gB + 16 * 4096,      &sBbuf[0][0][0] + ld1);
  gload_lds16(gA + 32,             &sAbuf[0][1][0] + ld0);
  gload_lds16(gA + 32 + 16 * 4096, &sAbuf[0][1][0] + ld1);
  gload_lds16(gB + 32,             &sBbuf[0][1][0] + ld0);
  gload_lds16(gB + 32 + 16 * 4096, &sBbuf[0][1][0] + ld1);
  VMW(4);   // A-kh0, B-kh0 of tile 0 arrived
  BAR;

  for (int i = 0; i < 31; ++i) {
    const int t1 = 2 * i + 1, t2 = 2 * i + 2;
    PHASE_BODY(0, 0, 0, 1, &sAbuf[1][0][0], gA, t1, 0);          BAR;
    PHASE_BODY(0, 0, 1, 1, &sBbuf[1][0][0], gB, t1, 0); VMW(4);  BAR;
    PHASE_BODY(0, 1, 0, 1, &sAbuf[1][1][0], gA, t1, 1);          BAR;
    PHASE_BODY(0, 1, 1, 1, &sBbuf[1][1][0], gB, t1, 1); VMW(4);  BAR;
    PHASE_BODY(1, 0, 0, 1, &sAbuf[0][0][0], gA, t2, 0);          BAR;
    PHASE_BODY(1, 0, 1, 1, &sBbuf[0][0][0], gB, t2, 0); VMW(4);  BAR;
    PHASE_BODY(1, 1, 0, 1, &sAbuf[0][1][0], gA, t2, 1);          BAR;
    PHASE_BODY(1, 1, 1, 1, &sBbuf[0][1][0], gB, t2, 1); VMW(4);  BAR;
  }
  // peeled last iteration (i = 31): stage tile 63 only; drain with vmcnt(0)
  PHASE_BODY(0, 0, 0, 1, &sAbuf[1][0][0], gA, 63, 0);            BAR;
  PHASE_BODY(0, 0, 1, 1, &sBbuf[1][0][0], gB, 63, 0); VMW(4);    BAR;
  PHASE_BODY(0, 1, 0, 1, &sAbuf[1][1][0], gA, 63, 1);            BAR;
  PHASE_BODY(0, 1, 1, 1, &sBbuf[1][1][0], gB, 63, 1); VMW(0);    BAR;
  PHASE_BODY(1, 0, 0, 0, &sAbuf[0][0][0], gA, 0, 0);             BAR;
  PHASE_BODY(1, 0, 1, 0, &sAbuf[0][0][0], gA, 0, 0);             BAR;
  PHASE_BODY(1, 1, 0, 0, &sAbuf[0][0][0], gA, 0, 0);             BAR;
  PHASE_BODY(1, 1, 1, 0, &sAbuf[0][0][0], gA, 0, 0);

#undef PHASE_BODY

  // epilogue: C write (bf16)
  const int crow0 = bm * 256 + wm * 128 + (lane >> 4) * 4;
  const int ccol0 = bn * 256 + wn * 64 + (lane & 15);
#pragma unroll
  for (int mf = 0; mf < 8; mf++)
#pragma unroll
    for (int nf = 0; nf < 4; nf++)
#pragma unroll
      for (int j = 0; j < 4; j++)
        C[(size_t)(crow0 + mf * 16 + j) * 4096 + ccol0 + nf * 16] = f2bf(acc[mf][nf][j]);
}

// ---------------------------------------------------------------------------
// K5: expanded[s][h][d] = post[h]*out[s][d] + sum_k comb[h][k]*hs[s][k][d]
__global__ __launch_bounds__(256) void k_expand(const float* __restrict__ hs,
                                                const unsigned short* __restrict__ outb,
                                                const float* __restrict__ gates,
                                                float* __restrict__ y) {
  const int s = blockIdx.x, tid = threadIdx.x;
  const float* g = gates + (size_t)s * MIXN;
  float post[4], cb[4][4];
#pragma unroll
  for (int h = 0; h < 4; h++) post[h] = g[4 + h];
#pragma unroll
  for (int h = 0; h < 4; h++)
#pragma unroll
    for (int k = 0; k < 4; k++) cb[h][k] = g[8 + h * 4 + k];

  const size_t base = (size_t)s * HC_N * H_DIM;
#pragma unroll
  for (int it = 0; it < 4; ++it) {
    const int d4 = it * 256 + tid;
    f32x4 hv[4];
#pragma unroll
    for (int k = 0; k < 4; k++)
      hv[k] = *(const f32x4*)(hs + base + (size_t)k * H_DIM + (size_t)d4 * 4);
    u16x4 ob = *(const u16x4*)(outb + (size_t)s * H_DIM + (size_t)d4 * 4);
    f32x4 o = {bf2f(ob[0]), bf2f(ob[1]), bf2f(ob[2]), bf2f(ob[3])};
#pragma unroll
    for (int h = 0; h < 4; h++) {
      f32x4 e = post[h] * o + cb[h][0] * hv[0] + cb[h][1] * hv[1] + cb[h][2] * hv[2] + cb[h][3] * hv[3];
      *(f32x4*)(y + base + (size_t)h * H_DIM + (size_t)d4 * 4) = e;
    }
  }
}

// ---------------------------------------------------------------------------
extern "C" void kernel_launch(void* const* d_in, const int* in_sizes, int n_in,
                              void* d_out, int out_size, void* d_ws, size_t ws_size,
                              hipStream_t stream) {
  const float* hs = (const float*)d_in[0];      // [1,4096,4,4096]
  const float* fn = (const float*)d_in[1];      // [24,16384]
  const float* hbase = (const float*)d_in[2];   // [24]
  const float* hscale = (const float*)d_in[3];  // [3]
  const float* nw = (const float*)d_in[4];      // [4096]
  const float* wi = (const float*)d_in[5];      // [4096,4096]
  float* y = (float*)d_out;                     // [1,4096,4,4096] fp32

  char* ws = (char*)d_ws;
  float* gates = (float*)(ws);                                          // 393216 B
  unsigned short* normed = (unsigned short*)(ws + 1048576);             // 32MB bf16
  unsigned short* wb = (unsigned short*)(ws + 1048576 + 33554432);      // 32MB bf16
  unsigned short* outb = (unsigned short*)(ws + 1048576 + 2 * 33554432);// 32MB bf16
  // total ws use: ~97MB

  k_w2bf<<<8192, 256, 0, stream>>>(wi, wb);
  k_mixes<<<512, 256, 0, stream>>>(hs, fn, hbase, hscale, gates);
  k_reduce_norm<<<4096, 256, 0, stream>>>(hs, gates, nw, normed);
  k_gemm<<<256, 512, 0, stream>>>(normed, wb, outb);
  k_expand<<<4096, 256, 0, stream>>>(hs, outb, gates, y);
}

// Round 8
// 484.340 us; speedup vs baseline: 1.1707x; 1.1707x over previous
//
#include <hip/hip_runtime.h>
#include <math.h>

// Problem dims (fixed by the reference)
#define S_DIM 4096
#define H_DIM 4096
#define HC_N 4
#define HD_DIM 16384   // HC_N * H_DIM
#define MIXN 24        // (2+HC)*HC
#define SINK_IT 20

typedef float f32x4 __attribute__((ext_vector_type(4)));
typedef __bf16 bf16x8 __attribute__((ext_vector_type(8)));
typedef unsigned short u16x8 __attribute__((ext_vector_type(8)));
typedef unsigned short u16x4 __attribute__((ext_vector_type(4)));

__device__ __forceinline__ unsigned short f2bf(float f) {
  unsigned u = __builtin_bit_cast(unsigned, f);
  u += 0x7FFFu + ((u >> 16) & 1u);   // round-to-nearest-even
  return (unsigned short)(u >> 16);
}
__device__ __forceinline__ float bf2f(unsigned short h) {
  return __builtin_bit_cast(float, (unsigned)h << 16);
}

// ---------------------------------------------------------------------------
// K0: w_inner fp32 -> bf16
__global__ __launch_bounds__(256) void k_w2bf(const float* __restrict__ w,
                                              unsigned short* __restrict__ wb) {
  const size_t i = (size_t)(blockIdx.x * 256 + threadIdx.x) * 8;
  f32x4 a = *(const f32x4*)(w + i);
  f32x4 b = *(const f32x4*)(w + i + 4);
  u16x8 o;
  o[0] = f2bf(a.x); o[1] = f2bf(a.y); o[2] = f2bf(a.z); o[3] = f2bf(a.w);
  o[4] = f2bf(b.x); o[5] = f2bf(b.y); o[6] = f2bf(b.z); o[7] = f2bf(b.w);
  *(u16x8*)(wb + i) = o;
}

// ---------------------------------------------------------------------------
// K1: per-row mixes_raw[s][24] = flat[s,:] . hc_fn[m,:]  and sumsq[s]
// ROUND-2 PROVEN STRUCTURE (restored verbatim): 4 rows per block, 1024 blocks
// -> 4 blocks/CU resident; block-level interleave hides hs-HBM under fn-L2 +
// FMA of other blocks (m114 mechanism). 8-row variant (2 blocks/CU, occ 10%)
// and fused k_row (2 blocks/CU serial phases) both regressed ~2x.
__global__ __launch_bounds__(256) void k_mixes(const float* __restrict__ hs,
                                               const float* __restrict__ fn,
                                               float* __restrict__ mixraw,
                                               float* __restrict__ sumsq) {
  __shared__ __align__(16) float lds[HC_N][1024];
  const int tid = threadIdx.x;
  const int b = blockIdx.x;          // rows 4b..4b+3
  const int lane = tid & 63, wave = tid >> 6;
  const int mbase = wave * 6;

  float acc[HC_N][6];
  float ss[HC_N];
#pragma unroll
  for (int r = 0; r < HC_N; r++) {
    ss[r] = 0.f;
#pragma unroll
    for (int j = 0; j < 6; j++) acc[r][j] = 0.f;
  }

  const size_t rowbase = (size_t)b * HC_N * HD_DIM;
  for (int it = 0; it < 16; ++it) {
    __syncthreads();   // previous compute done before overwriting LDS
#pragma unroll
    for (int r = 0; r < HC_N; r++) {
      f32x4 v = *(const f32x4*)(hs + rowbase + (size_t)r * HD_DIM + it * 1024 + tid * 4);
      *(f32x4*)(&lds[r][tid * 4]) = v;
    }
    __syncthreads();
#pragma unroll
    for (int ii = 0; ii < 4; ii++) {
      const int c4 = ii * 64 + lane;   // f32x4 index within the 1024-float chunk
      f32x4 h4[HC_N];
#pragma unroll
      for (int r = 0; r < HC_N; r++) h4[r] = *(const f32x4*)(&lds[r][c4 * 4]);
      if (wave == 0) {
#pragma unroll
        for (int r = 0; r < HC_N; r++)
          ss[r] += h4[r].x * h4[r].x + h4[r].y * h4[r].y + h4[r].z * h4[r].z + h4[r].w * h4[r].w;
      }
#pragma unroll
      for (int j = 0; j < 6; j++) {
        f32x4 fv = *(const f32x4*)(fn + (size_t)(mbase + j) * HD_DIM + it * 1024 + c4 * 4);
#pragma unroll
        for (int r = 0; r < HC_N; r++)
          acc[r][j] += h4[r].x * fv.x + h4[r].y * fv.y + h4[r].z * fv.z + h4[r].w * fv.w;
      }
    }
  }

  // per-wave shuffle reduction; each wave owns its 6 m values outright
#pragma unroll
  for (int r = 0; r < HC_N; r++) {
#pragma unroll
    for (int j = 0; j < 6; j++) {
      float v = acc[r][j];
#pragma unroll
      for (int off = 32; off >= 1; off >>= 1) v += __shfl_xor(v, off, 64);
      if (lane == 0) mixraw[(size_t)(b * 4 + r) * MIXN + mbase + j] = v;
    }
  }
  if (wave == 0) {
#pragma unroll
    for (int r = 0; r < HC_N; r++) {
      float v = ss[r];
#pragma unroll
      for (int off = 32; off >= 1; off >>= 1) v += __shfl_xor(v, off, 64);
      if (lane == 0) sumsq[b * 4 + r] = v;
    }
  }
}

// ---------------------------------------------------------------------------
// K2: gates = {pre[4], post[4], sinkhorn(comb)[16]} per row
__global__ __launch_bounds__(256) void k_gates(const float* __restrict__ mixraw,
                                               const float* __restrict__ sumsq,
                                               const float* __restrict__ hbase,
                                               const float* __restrict__ hscale,
                                               float* __restrict__ gates) {
  const int row = blockIdx.x * 256 + threadIdx.x;
  const float rs = rsqrtf(sumsq[row] * (1.0f / HD_DIM) + 1e-6f);
  const float ps = hscale[0], qs = hscale[1], cs = hscale[2];
  const float* mr = mixraw + (size_t)row * MIXN;
  float g[MIXN];
#pragma unroll
  for (int m = 0; m < MIXN; m++) {
    const float sc = (m < 4) ? ps : ((m < 8) ? qs : cs);
    const float x = mr[m] * rs * sc + hbase[m];
    g[m] = 1.0f / (1.0f + expf(-x)) + 1e-6f;
  }
  // 20-iter Sinkhorn on g[8..23] viewed as c[i][j] = g[8+i*4+j]
  for (int t = 0; t < SINK_IT; t++) {
#pragma unroll
    for (int i = 0; i < 4; i++) {
      const float s = g[8 + i * 4 + 0] + g[8 + i * 4 + 1] + g[8 + i * 4 + 2] + g[8 + i * 4 + 3] + 1e-6f;
#pragma unroll
      for (int j = 0; j < 4; j++) g[8 + i * 4 + j] /= s;
    }
#pragma unroll
    for (int j = 0; j < 4; j++) {
      const float s = g[8 + 0 + j] + g[8 + 4 + j] + g[8 + 8 + j] + g[8 + 12 + j] + 1e-6f;
#pragma unroll
      for (int i = 0; i < 4; i++) g[8 + i * 4 + j] /= s;
    }
  }
  float* go = gates + (size_t)row * MIXN;
#pragma unroll
  for (int m = 0; m < MIXN; m++) go[m] = g[m];
}

// ---------------------------------------------------------------------------
// K3: reduced = pre . hs  -> RMSNorm -> normed (bf16).  One block per row s.
__global__ __launch_bounds__(256) void k_reduce_norm(const float* __restrict__ hs,
                                                     const float* __restrict__ gates,
                                                     const float* __restrict__ nw,
                                                     unsigned short* __restrict__ normed) {
  const int s = blockIdx.x, tid = threadIdx.x;
  const int lane = tid & 63, wave = tid >> 6;
  const float* g = gates + (size_t)s * MIXN;
  const float p0 = g[0], p1 = g[1], p2 = g[2], p3 = g[3];
  const size_t base = (size_t)s * HC_N * H_DIM;

  f32x4 red[4];
  float ssq = 0.f;
#pragma unroll
  for (int it = 0; it < 4; ++it) {
    const int d4 = it * 256 + tid;
    f32x4 a = *(const f32x4*)(hs + base + (size_t)0 * H_DIM + (size_t)d4 * 4);
    f32x4 b = *(const f32x4*)(hs + base + (size_t)1 * H_DIM + (size_t)d4 * 4);
    f32x4 c = *(const f32x4*)(hs + base + (size_t)2 * H_DIM + (size_t)d4 * 4);
    f32x4 d = *(const f32x4*)(hs + base + (size_t)3 * H_DIM + (size_t)d4 * 4);
    f32x4 v = p0 * a + p1 * b + p2 * c + p3 * d;
    red[it] = v;
    ssq += v.x * v.x + v.y * v.y + v.z * v.z + v.w * v.w;
  }
#pragma unroll
  for (int off = 32; off >= 1; off >>= 1) ssq += __shfl_xor(ssq, off, 64);
  __shared__ float ls[4];
  if (lane == 0) ls[wave] = ssq;
  __syncthreads();
  const float tot = ls[0] + ls[1] + ls[2] + ls[3];
  const float nr = rsqrtf(tot * (1.0f / H_DIM) + 1e-6f);
#pragma unroll
  for (int it = 0; it < 4; ++it) {
    const int d4 = it * 256 + tid;
    f32x4 w = *(const f32x4*)(nw + (size_t)d4 * 4);
    f32x4 v = red[it] * nr;
    v = v * w;
    u16x4 o;
    o[0] = f2bf(v.x); o[1] = f2bf(v.y); o[2] = f2bf(v.z); o[3] = f2bf(v.w);
    *(u16x4*)(normed + (size_t)s * H_DIM + (size_t)d4 * 4) = o;
  }
}

// ---------------------------------------------------------------------------
// K4: bf16 GEMM  C[s][e] = sum_d A[s][d] * B[e][d]
// 256x256 tile, 8-phase schedule + rule-#18 fences. Round-7 change: CORRECT
// bijective bank-quad swizzle. Old swz = chunk^(row&3) gave quad =
// (4row+swz)%8 with period 4 -> still 4-way conflict (counter unchanged at
// 1.258e7). New swz = chunk ^ ((row>>1)&3): quads {0,4,1,5,2,6,3,7} over 8
// rows -> 2 lanes/quad = free (m136). Stage side pre-swizzles the GLOBAL
// source (linear gload_lds dest); read side XORs the same involution. All
// row bases are multiples of 16, so both reduce to lane-constant XORs.
// PRE-COMMITTED READ: conflict <3e6 + dur drop => conflicts were the pole;
// conflict <3e6 + dur null => issue/barrier-bound, freeze k_gemm.
__device__ __forceinline__ void gload_lds16(const unsigned short* g, unsigned short* l) {
  __builtin_amdgcn_global_load_lds(
      (const __attribute__((address_space(1))) unsigned int*)(const void*)g,
      (__attribute__((address_space(3))) unsigned int*)(void*)l, 16, 0, 0);
}

#define VMW(n) asm volatile("s_waitcnt vmcnt(" #n ")" ::: "memory")
#define BAR    asm volatile("s_barrier" ::: "memory")
#define LGK0   asm volatile("s_waitcnt lgkmcnt(0)" ::: "memory")
#define SCB    __builtin_amdgcn_sched_barrier(0)

__global__ __launch_bounds__(512, 2) void k_gemm(const unsigned short* __restrict__ A,
                                                 const unsigned short* __restrict__ B,
                                                 unsigned short* __restrict__ C) {
  __shared__ __align__(16) unsigned short sAbuf[2][2][256 * 32];
  __shared__ __align__(16) unsigned short sBbuf[2][2][256 * 32];
  const int tid = threadIdx.x;
  const int lane = tid & 63, wave = tid >> 6;

  // Bijective XCD swizzle (256 blocks % 8 == 0): XCD v owns bn in {2v,2v+1}.
  const int bid = blockIdx.x;
  const int v = bid & 7, u = bid >> 3;          // u in 0..31
  const int bm = u & 15, bn = v * 2 + (u >> 4);
  const int wm = wave >> 2, wn = wave & 3;      // 2x4 wave grid, 128x64 per wave

  // staging: wave stages rows [wave*32, +32) of a [256][32] k-half, 2 instr.
  // Pre-swizzled global source: logical chunk = (lane&3) ^ ((row>>1)&3),
  // row = lane>>2 (row>>1 bits == lane>>3; +16/+32 offsets are %4-invariant).
  const int srow = lane >> 2;                              // 0..15
  const int sk8 = (((lane & 3) ^ ((lane >> 3) & 3)) * 8);  // swizzled k-offset
  const unsigned short* gA = A + (size_t)(bm * 256 + wave * 32 + srow) * 4096 + sk8;
  const unsigned short* gB = B + (size_t)(bn * 256 + wave * 32 + srow) * 4096 + sk8;
  const int ld0 = wave * 1024 + lane * 8;   // element offset, instr 0 (linear dest)
  const int ld1 = ld0 + 512;                // rows +16..31

  f32x4 acc[8][4];
  f32x4 zero = {0.f, 0.f, 0.f, 0.f};
#pragma unroll
  for (int mf = 0; mf < 8; mf++)
#pragma unroll
    for (int nf = 0; nf < 4; nf++) acc[mf][nf] = zero;
  bf16x8 af[8];

  // fragment read: row = base16 + (lane&15); phys chunk = (lane>>4) ^ ((row>>1)&3)
  const int frow = lane & 15;
  const int fk = (((lane >> 4) ^ ((lane >> 1) & 3)) * 8);   // swizzled read offset

#define PHASE_BODY(db, kh, nh, dostg, sdst, gsrc, t, skh) do {                  \
    if ((nh) == 0) {                                                            \
      _Pragma("unroll") for (int mf = 0; mf < 8; mf++)                          \
        af[mf] = *(const bf16x8*)&sAbuf[db][kh][(wm * 128 + mf * 16 + frow) * 32 + fk]; \
    }                                                                           \
    bf16x8 b0 = *(const bf16x8*)&sBbuf[db][kh][(wn * 64 + ((nh) * 2 + 0) * 16 + frow) * 32 + fk]; \
    bf16x8 b1 = *(const bf16x8*)&sBbuf[db][kh][(wn * 64 + ((nh) * 2 + 1) * 16 + frow) * 32 + fk]; \
    if (dostg) {                                                                \
      const unsigned short* _g = (gsrc) + (size_t)(t) * 64 + (skh) * 32;        \
      gload_lds16(_g,              (sdst) + ld0);                               \
      gload_lds16(_g + 16 * 4096,  (sdst) + ld1);                               \
    }                                                                           \
    SCB;                                                                        \
    BAR;                                                                        \
    LGK0;                                                                       \
    SCB;                                                                        \
    __builtin_amdgcn_s_setprio(1);                                              \
    _Pragma("unroll") for (int mf = 0; mf < 8; mf++) {                          \
      acc[mf][(nh) * 2 + 0] = __builtin_amdgcn_mfma_f32_16x16x32_bf16(af[mf], b0, acc[mf][(nh) * 2 + 0], 0, 0, 0); \
      acc[mf][(nh) * 2 + 1] = __builtin_amdgcn_mfma_f32_16x16x32_bf16(af[mf], b1, acc[mf][(nh) * 2 + 1], 0, 0, 0); \
    }                                                                           \
    __builtin_amdgcn_s_setprio(0);                                              \
    SCB;                                                                        \
  } while (0)

  // prologue: tile 0 -> db0 in order A-kh0, B-kh0, A-kh1, B-kh1
  gload_lds16(gA,                  &sAbuf[0][0][0] + ld0);
  gload_lds16(gA + 16 * 4096,      &sAbuf[0][0][0] + ld1);
  gload_lds16(gB,                  &sBbuf[0][0][0] + ld0);
  gload_lds16(gB + 16 * 4096,      &sBbuf[0][0][0] + ld1);
  gload_lds16(gA + 32,             &sAbuf[0][1][0] + ld0);
  gload_lds16(gA + 32 + 16 * 4096, &sAbuf[0][1][0] + ld1);
  gload_lds16(gB + 32,             &sBbuf[0][1][0] + ld0);
  gload_lds16(gB + 32 + 16 * 4096, &sBbuf[0][1][0] + ld1);
  VMW(4);   // A-kh0, B-kh0 of tile 0 arrived
  BAR;

  for (int i = 0; i < 31; ++i) {
    const int t1 = 2 * i + 1, t2 = 2 * i + 2;
    PHASE_BODY(0, 0, 0, 1, &sAbuf[1][0][0], gA, t1, 0);          BAR;
    PHASE_BODY(0, 0, 1, 1, &sBbuf[1][0][0], gB, t1, 0); VMW(4);  BAR;
    PHASE_BODY(0, 1, 0, 1, &sAbuf[1][1][0], gA, t1, 1);          BAR;
    PHASE_BODY(0, 1, 1, 1, &sBbuf[1][1][0], gB, t1, 1); VMW(4);  BAR;
    PHASE_BODY(1, 0, 0, 1, &sAbuf[0][0][0], gA, t2, 0);          BAR;
    PHASE_BODY(1, 0, 1, 1, &sBbuf[0][0][0], gB, t2, 0); VMW(4);  BAR;
    PHASE_BODY(1, 1, 0, 1, &sAbuf[0][1][0], gA, t2, 1);          BAR;
    PHASE_BODY(1, 1, 1, 1, &sBbuf[0][1][0], gB, t2, 1); VMW(4);  BAR;
  }
  // peeled last iteration (i = 31): stage tile 63 only; drain with vmcnt(0)
  PHASE_BODY(0, 0, 0, 1, &sAbuf[1][0][0], gA, 63, 0);            BAR;
  PHASE_BODY(0, 0, 1, 1, &sBbuf[1][0][0], gB, 63, 0); VMW(4);    BAR;
  PHASE_BODY(0, 1, 0, 1, &sAbuf[1][1][0], gA, 63, 1);            BAR;
  PHASE_BODY(0, 1, 1, 1, &sBbuf[1][1][0], gB, 63, 1); VMW(0);    BAR;
  PHASE_BODY(1, 0, 0, 0, &sAbuf[0][0][0], gA, 0, 0);             BAR;
  PHASE_BODY(1, 0, 1, 0, &sAbuf[0][0][0], gA, 0, 0);             BAR;
  PHASE_BODY(1, 1, 0, 0, &sAbuf[0][0][0], gA, 0, 0);             BAR;
  PHASE_BODY(1, 1, 1, 0, &sAbuf[0][0][0], gA, 0, 0);

#undef PHASE_BODY

  // epilogue: C write (bf16)
  const int crow0 = bm * 256 + wm * 128 + (lane >> 4) * 4;
  const int ccol0 = bn * 256 + wn * 64 + (lane & 15);
#pragma unroll
  for (int mf = 0; mf < 8; mf++)
#pragma unroll
    for (int nf = 0; nf < 4; nf++)
#pragma unroll
      for (int j = 0; j < 4; j++)
        C[(size_t)(crow0 + mf * 16 + j) * 4096 + ccol0 + nf * 16] = f2bf(acc[mf][nf][j]);
}

// ---------------------------------------------------------------------------
// K5: expanded[s][h][d] = post[h]*out[s][d] + sum_k comb[h][k]*hs[s][k][d]
__global__ __launch_bounds__(256) void k_expand(const float* __restrict__ hs,
                                                const unsigned short* __restrict__ outb,
                                                const float* __restrict__ gates,
                                                float* __restrict__ y) {
  const int s = blockIdx.x, tid = threadIdx.x;
  const float* g = gates + (size_t)s * MIXN;
  float post[4], cb[4][4];
#pragma unroll
  for (int h = 0; h < 4; h++) post[h] = g[4 + h];
#pragma unroll
  for (int h = 0; h < 4; h++)
#pragma unroll
    for (int k = 0; k < 4; k++) cb[h][k] = g[8 + h * 4 + k];

  const size_t base = (size_t)s * HC_N * H_DIM;
#pragma unroll
  for (int it = 0; it < 4; ++it) {
    const int d4 = it * 256 + tid;
    f32x4 hv[4];
#pragma unroll
    for (int k = 0; k < 4; k++)
      hv[k] = *(const f32x4*)(hs + base + (size_t)k * H_DIM + (size_t)d4 * 4);
    u16x4 ob = *(const u16x4*)(outb + (size_t)s * H_DIM + (size_t)d4 * 4);
    f32x4 o = {bf2f(ob[0]), bf2f(ob[1]), bf2f(ob[2]), bf2f(ob[3])};
#pragma unroll
    for (int h = 0; h < 4; h++) {
      f32x4 e = post[h] * o + cb[h][0] * hv[0] + cb[h][1] * hv[1] + cb[h][2] * hv[2] + cb[h][3] * hv[3];
      *(f32x4*)(y + base + (size_t)h * H_DIM + (size_t)d4 * 4) = e;
    }
  }
}

// ---------------------------------------------------------------------------
extern "C" void kernel_launch(void* const* d_in, const int* in_sizes, int n_in,
                              void* d_out, int out_size, void* d_ws, size_t ws_size,
                              hipStream_t stream) {
  const float* hs = (const float*)d_in[0];      // [1,4096,4,4096]
  const float* fn = (const float*)d_in[1];      // [24,16384]
  const float* hbase = (const float*)d_in[2];   // [24]
  const float* hscale = (const float*)d_in[3];  // [3]
  const float* nw = (const float*)d_in[4];      // [4096]
  const float* wi = (const float*)d_in[5];      // [4096,4096]
  float* y = (float*)d_out;                     // [1,4096,4,4096] fp32

  char* ws = (char*)d_ws;
  float* mixraw = (float*)(ws);                            // 4096*24*4   = 393216
  float* sumsq = (float*)(ws + 393216);                    // 4096*4      = 16384
  float* gates = (float*)(ws + 409600);                    // 4096*24*4   = 393216
  unsigned short* normed = (unsigned short*)(ws + 1048576);            // 32MB bf16
  unsigned short* wb = (unsigned short*)(ws + 1048576 + 33554432);     // 32MB bf16
  unsigned short* outb = (unsigned short*)(ws + 1048576 + 2 * 33554432); // 32MB bf16
  // total ws use: ~97MB

  k_w2bf<<<8192, 256, 0, stream>>>(wi, wb);
  k_mixes<<<1024, 256, 0, stream>>>(hs, fn, mixraw, sumsq);
  k_gates<<<16, 256, 0, stream>>>(mixraw, sumsq, hbase, hscale, gates);
  k_reduce_norm<<<4096, 256, 0, stream>>>(hs, gates, nw, normed);
  k_gemm<<<256, 512, 0, stream>>>(normed, wb, outb);
  k_expand<<<4096, 256, 0, stream>>>(hs, outb, gates, y);
}